// Round 4
// baseline (6329.537 us; speedup 1.0000x reference)
//
#include <hip/hip_runtime.h>

// ---------------------------------------------------------------------------
// Persistent 2-layer LSTM, MI355X. Round 4.
// 8 groups (blockIdx%8), 32 WGs/group, 8 batches/group. Weights in VGPRs.
// Coherence: all h-plane traffic uses relaxed SYSTEM-scope (sc0|sc1 bypass)
// ops -> coherent at LLC by construction; zero cache-maintenance ops.
// Round-4: conflict-free staging (was 16-way banked), persistent plane A
// (h0 staged once/step, reused by layer-1 GEMM AND next step's layer-0 GEMM
// moved into the tail), all-thread relaxed spin, wave0-local publish with
// inline s_waitcnt. 6 syncthreads/step (was ~10), 2 stages/step (was 3).
// ---------------------------------------------------------------------------

#define T_STEPS 1024
#define WS_BAR_OFF 0                      // 8 groups * 2 counters * 128 B
#define WS_H0_OFF  2048                   // [8 g][2 parity][8 batch][512] f16
#define WS_H1_OFF  (2048 + 8*2*8*512*2)
#define WS_NEED    (WS_H1_OFF + 8*2*8*512*2)   // 264192 bytes

typedef _Float16 f16;
typedef _Float16 f16x8 __attribute__((ext_vector_type(8)));
typedef float    f32x4 __attribute__((ext_vector_type(4)));
typedef unsigned long long u64;

#define HP_STRIDE 520   // padded LDS plane row stride (f16)

__device__ __forceinline__ float sigm_(float x) {
    x = fminf(fmaxf(x, -30.f), 30.f);
    return 1.f / (1.f + __expf(-x));
}
__device__ __forceinline__ float tanh_(float x) {
    x = fminf(fmaxf(x, -15.f), 15.f);
    float e = __expf(-2.f * x);
    return (1.f - e) / (1.f + e);
}

// A-fragment for 16x16x32 f16 MFMA from a padded LDS plane.
// A[m=lane&15][k=(lane>>4)*8+j]; m = batch (0..7 valid, 8..15 -> zeros).
__device__ __forceinline__ f16x8 afrag_lds(const f16* __restrict__ hp, int kbase,
                                           int b, int q) {
    if (b < 8) {
        return *(const f16x8*)(hp + b * HP_STRIDE + kbase + q * 8);
    }
    f16x8 z = {(_Float16)0, (_Float16)0, (_Float16)0, (_Float16)0,
               (_Float16)0, (_Float16)0, (_Float16)0, (_Float16)0};
    return z;
}

__device__ __forceinline__ f16x8 pack8(float4 a, float4 b) {
    f16x8 f;
    f[0] = (f16)a.x; f[1] = (f16)a.y; f[2] = (f16)a.z; f[3] = (f16)a.w;
    f[4] = (f16)b.x; f[5] = (f16)b.y; f[6] = (f16)b.z; f[7] = (f16)b.w;
    return f;
}

// Stage one 8 KB h-plane into padded LDS. Lane-contiguous per instruction:
// global load j reads u64 index j*256+tid (coalesced 2 KB/instr, bypass sc0|sc1);
// LDS write lane stride 8 B -> <=4-way aliasing (round-3's 32 B stride was
// 16-way -> 2.2e8 conflict cycles).
__device__ __forceinline__ void stage_plane(const f16* __restrict__ gp,
                                            f16* __restrict__ dst, int tid) {
    const u64* g8 = (const u64*)gp;
    u64 v[4];
#pragma unroll
    for (int j = 0; j < 4; ++j)
        v[j] = __hip_atomic_load(g8 + j * 256 + tid, __ATOMIC_RELAXED,
                                 __HIP_MEMORY_SCOPE_SYSTEM);
#pragma unroll
    for (int j = 0; j < 4; ++j) {
        int idx = (j * 256 + tid) * 4;            // f16 index in plane
        int b = idx >> 9, u = idx & 511;
        *(u64*)(dst + b * HP_STRIDE + u) = v[j];
    }
}

// All threads poll (uniform address -> 1 memory request per wave). No
// cache-maintenance per iteration; the data path is coherent by construction.
__device__ __forceinline__ void spin_all(unsigned* cnt, unsigned target) {
    int spins = 0;
    while (__hip_atomic_load(cnt, __ATOMIC_RELAXED, __HIP_MEMORY_SCOPE_AGENT) < target) {
        __builtin_amdgcn_s_sleep(1);
        if (++spins > (1 << 22)) break;   // anti-hang safety valve
    }
}

// x A-fragment for step t (zeros if t out of range).
__device__ __forceinline__ f16x8 load_xfrag(const float* __restrict__ x,
                                            int gb8, int t, int ln, int q) {
    f16x8 f = {(_Float16)0, (_Float16)0, (_Float16)0, (_Float16)0,
               (_Float16)0, (_Float16)0, (_Float16)0, (_Float16)0};
    if (ln < 8 && t < T_STEPS) {
        const float* xp = x + ((size_t)(gb8 + ln) * 1024 + t) * 21;
#pragma unroll
        for (int j = 0; j < 8; ++j) {
            int kl = q * 8 + j;
            if (kl < 21) f[j] = (f16)xp[kl];
        }
    }
    return f;
}

__global__ void zero_ws_kernel(unsigned* __restrict__ p, int ndw) {
    int i = blockIdx.x * blockDim.x + threadIdx.x;
    int stride = gridDim.x * blockDim.x;
    for (; i < ndw; i += stride) p[i] = 0u;
}

__global__ __launch_bounds__(256, 1)
void lstm_persist(const float* __restrict__ x,
                  const float* __restrict__ Wx0, const float* __restrict__ bx0,
                  const float* __restrict__ Wh0,
                  const float* __restrict__ Wx1, const float* __restrict__ bx1,
                  const float* __restrict__ Wh1,
                  const float* __restrict__ Wo,  const float* __restrict__ bo,
                  float* __restrict__ out, char* __restrict__ ws) {
    struct SM {
        float g[4][16][16];                      // per-wave gate tiles
        float c[2][8][16];                       // cell state [layer][b][u]
        float bias[2][4][16];                    // bx slices
        __align__(8)  f16 hout[8][16];           // activation -> packed store
        __align__(16) f16 planeA[8 * HP_STRIDE]; // persistent h0 plane
        __align__(16) f16 planeB[8 * HP_STRIDE]; // h1 scratch plane
        char  pad[70 * 1024];                    // force <=1 WG/CU
    };
    __shared__ SM sm;
    const int tid = threadIdx.x;
    if (tid == 0x00FFFFFFu) sm.pad[0] = 1;       // keep pad alive

    const int bid  = blockIdx.x;
    const int g    = bid & 7;     // group
    const int cu   = bid >> 3;    // 0..31 within group
    const int w    = tid >> 6;    // wave id = gate type (i,f,g,o)
    const int lane = tid & 63;
    const int ln   = lane & 15;
    const int q    = lane >> 4;
    const int gb8  = g * 8;       // first batch of group

    unsigned* cntA = (unsigned*)(ws + WS_BAR_OFF) + g * 64;        // h0 barrier
    unsigned* cntB = (unsigned*)(ws + WS_BAR_OFF) + g * 64 + 32;   // h1 barrier
    f16* H0g = (f16*)(ws + WS_H0_OFF) + g * 8192;   // 2 parity planes
    f16* H1g = (f16*)(ws + WS_H1_OFF) + g * 8192;

    // ---- LDS init -------------------------------------------------------
    ((float*)sm.c)[tid & 255] = 0.f;               // 2*8*16 = 256 floats
    if (tid < 128) {
        int u = tid & 15, w2 = (tid >> 4) & 3, L = tid >> 6;
        const float* bx = L ? bx1 : bx0;
        sm.bias[L][w2][u] = bx[(w2 << 9) + (cu << 4) + u];
    }

    // ---- persistent weight fragments in registers -----------------------
    const int row = (w << 9) + (cu << 4) + ln;      // gate row in [0,2048)
    f16x8 B0[17];   // layer0: k = [Wh0(512) ; Wx0(21 pad 32)]
    f16x8 B1[32];   // layer1: k = [Wx1(512) ; Wh1(512)]
    {
        const float* wh0r = Wh0 + (size_t)row * 512;
#pragma unroll
        for (int kk = 0; kk < 16; ++kk) {
            const float* p = wh0r + kk * 32 + q * 8;
            B0[kk] = pack8(*(const float4*)p, *(const float4*)(p + 4));
        }
        {
            const float* wx0r = Wx0 + (size_t)row * 21;
            f16x8 f;
#pragma unroll
            for (int j = 0; j < 8; ++j) {
                int kl = q * 8 + j;
                f[j] = (f16)((kl < 21) ? wx0r[kl] : 0.f);
            }
            B0[16] = f;
        }
        const float* wx1r = Wx1 + (size_t)row * 512;
        const float* wh1r = Wh1 + (size_t)row * 512;
#pragma unroll
        for (int kk = 0; kk < 32; ++kk) {
            int k0 = kk * 32 + q * 8;
            const float* p = (k0 < 512) ? (wx1r + k0) : (wh1r + (k0 - 512));
            B1[kk] = pack8(*(const float4*)p, *(const float4*)(p + 4));
        }
    }

    // ---- prologue: gates0(t=0) = Wx0 @ x(0)  (h0(-1)=0) ------------------
    {
        f16x8 xf = load_xfrag(x, gb8, 0, ln, q);
        f32x4 z = {0, 0, 0, 0};
        f32x4 acc = __builtin_amdgcn_mfma_f32_16x16x32_f16(xf, B0[16], z, 0, 0, 0);
#pragma unroll
        for (int r = 0; r < 4; ++r) sm.g[w][q * 4 + r][ln] = acc[r];
    }
    __syncthreads();

    for (int t = 0; t < T_STEPS; ++t) {
        const int wr = t & 1, rd = wr ^ 1;
        f16*       h0wr = H0g + wr * 4096;
        const f16* h1rd = H1g + rd * 4096;
        f16*       h1wr = H1g + wr * 4096;

        // ===== act0 + publish h0(t) (gates0 computed in prev tail) =========
        if (tid < 128) {
            int b = tid & 7, u = tid >> 3;
            float gi = sm.g[0][b][u] + sm.bias[0][0][u];
            float gf = sm.g[1][b][u] + sm.bias[0][1][u];
            float gg = sm.g[2][b][u] + sm.bias[0][2][u];
            float go = sm.g[3][b][u] + sm.bias[0][3][u];
            float iv = sigm_(gi), fv = sigm_(gf), gv = tanh_(gg), ov = sigm_(go);
            float c = sm.c[0][b][u];
            float cn = fv * c + iv * gv;
            sm.c[0][b][u] = cn;
            sm.hout[b][u] = (f16)(ov * tanh_(cn));
        }
        __syncthreads();
        if (tid < 32) {
            int b = tid >> 2, j = tid & 3;
            u64 v = *(const u64*)&sm.hout[b][j * 4];
            __hip_atomic_store((u64*)(h0wr + b * 512 + (cu << 4) + j * 4), v,
                               __ATOMIC_RELAXED, __HIP_MEMORY_SCOPE_SYSTEM);
        }
        if (tid < 64) {   // wave0-local drain, then signal: no syncthreads
            asm volatile("s_waitcnt vmcnt(0)" ::: "memory");
            if (tid == 0)
                __hip_atomic_fetch_add(cntA, 1u, __ATOMIC_RELAXED,
                                       __HIP_MEMORY_SCOPE_AGENT);
        }

        // ===== wait h1(t-1), stage plane B =================================
        spin_all(cntB, 32u * (unsigned)t);
        stage_plane(h1rd, sm.planeB, tid);
        __syncthreads();

        // ===== out-proj(t-1) on wave 1 + Wh1 @ h1(t-1) =====================
        if (t > 0 && tid >= 64 && tid < 128) {
            int wt = tid - 64;
            int pr = wt >> 3, kp = wt & 7;
            int idx = cu * 5 + pr;        // pr<5 valid
            int valid = (pr < 5);
            int b = valid ? idx / 20 : 0, o = valid ? idx % 20 : 0;
            const f16* hp = sm.planeB + b * HP_STRIDE + kp * 64;
            const float* wo = Wo + (size_t)o * 512 + kp * 64;
            float a = 0.f;
            if (valid) {
#pragma unroll
                for (int k = 0; k < 64; k += 8) {
                    f16x8 hv = *(const f16x8*)(hp + k);
                    float4 wa = *(const float4*)(wo + k);
                    float4 wb = *(const float4*)(wo + k + 4);
                    a += (float)hv[0] * wa.x + (float)hv[1] * wa.y +
                         (float)hv[2] * wa.z + (float)hv[3] * wa.w +
                         (float)hv[4] * wb.x + (float)hv[5] * wb.y +
                         (float)hv[6] * wb.z + (float)hv[7] * wb.w;
                }
            }
            a += __shfl_down(a, 4, 8);
            a += __shfl_down(a, 2, 8);
            a += __shfl_down(a, 1, 8);
            if (valid && kp == 0)
                out[((size_t)(gb8 + b) * 1024 + (t - 1)) * 20 + o] = sigm_(a + bo[o]);
        }
        f32x4 c0v = {0, 0, 0, 0}, c1v = {0, 0, 0, 0};
#pragma unroll
        for (int kk = 16; kk < 32; kk += 2) {
            f16x8 A0 = afrag_lds(sm.planeB, kk * 32 - 512, ln, q);
            f16x8 A1 = afrag_lds(sm.planeB, kk * 32 - 480, ln, q);
            c0v = __builtin_amdgcn_mfma_f32_16x16x32_f16(A0, B1[kk], c0v, 0, 0, 0);
            c1v = __builtin_amdgcn_mfma_f32_16x16x32_f16(A1, B1[kk + 1], c1v, 0, 0, 0);
        }

        // ===== wait h0(t), stage persistent plane A ========================
        spin_all(cntA, 32u * (unsigned)(t + 1));
        stage_plane(h0wr, sm.planeA, tid);
        __syncthreads();

        // ===== Wx1 @ h0(t) =================================================
#pragma unroll
        for (int kk = 0; kk < 16; kk += 2) {
            f16x8 A0 = afrag_lds(sm.planeA, kk * 32, ln, q);
            f16x8 A1 = afrag_lds(sm.planeA, kk * 32 + 32, ln, q);
            c0v = __builtin_amdgcn_mfma_f32_16x16x32_f16(A0, B1[kk], c0v, 0, 0, 0);
            c1v = __builtin_amdgcn_mfma_f32_16x16x32_f16(A1, B1[kk + 1], c1v, 0, 0, 0);
        }
        {
            f32x4 acc = c0v + c1v;
#pragma unroll
            for (int r = 0; r < 4; ++r) sm.g[w][q * 4 + r][ln] = acc[r];
        }
        __syncthreads();

        // ===== act1 + publish h1(t) ========================================
        if (tid < 128) {
            int b = tid & 7, u = tid >> 3;
            float gi = sm.g[0][b][u] + sm.bias[1][0][u];
            float gf = sm.g[1][b][u] + sm.bias[1][1][u];
            float gg = sm.g[2][b][u] + sm.bias[1][2][u];
            float go = sm.g[3][b][u] + sm.bias[1][3][u];
            float iv = sigm_(gi), fv = sigm_(gf), gv = tanh_(gg), ov = sigm_(go);
            float c = sm.c[1][b][u];
            float cn = fv * c + iv * gv;
            sm.c[1][b][u] = cn;
            sm.hout[b][u] = (f16)(ov * tanh_(cn));
        }
        __syncthreads();
        if (tid < 32) {
            int b = tid >> 2, j = tid & 3;
            u64 v = *(const u64*)&sm.hout[b][j * 4];
            __hip_atomic_store((u64*)(h1wr + b * 512 + (cu << 4) + j * 4), v,
                               __ATOMIC_RELAXED, __HIP_MEMORY_SCOPE_SYSTEM);
        }
        if (tid < 64) {
            asm volatile("s_waitcnt vmcnt(0)" ::: "memory");
            if (tid == 0)
                __hip_atomic_fetch_add(cntB, 1u, __ATOMIC_RELAXED,
                                       __HIP_MEMORY_SCOPE_AGENT);
        }

        // ===== tail: gates0(t+1) = Wh0 @ h0(t) + Wx0 @ x(t+1) ==============
        {
            f16x8 xf = load_xfrag(x, gb8, t + 1, ln, q);
            f32x4 a0 = {0, 0, 0, 0}, a1 = {0, 0, 0, 0};
#pragma unroll
            for (int kk = 0; kk < 16; kk += 2) {
                f16x8 A0 = afrag_lds(sm.planeA, kk * 32, ln, q);
                f16x8 A1 = afrag_lds(sm.planeA, kk * 32 + 32, ln, q);
                a0 = __builtin_amdgcn_mfma_f32_16x16x32_f16(A0, B0[kk], a0, 0, 0, 0);
                a1 = __builtin_amdgcn_mfma_f32_16x16x32_f16(A1, B0[kk + 1], a1, 0, 0, 0);
            }
            a0 = __builtin_amdgcn_mfma_f32_16x16x32_f16(xf, B0[16], a0, 0, 0, 0);
            f32x4 acc = a0 + a1;
#pragma unroll
            for (int r = 0; r < 4; ++r) sm.g[w][q * 4 + r][ln] = acc[r];
        }
        __syncthreads();
    }

    // ===== epilogue: out-projection for t = T-1 =============================
    spin_all(cntB, 32u * (unsigned)T_STEPS);
    stage_plane(H1g + ((T_STEPS - 1) & 1) * 4096, sm.planeB, tid);
    __syncthreads();
    if (tid >= 64 && tid < 128) {
        int wt = tid - 64;
        int pr = wt >> 3, kp = wt & 7;
        int idx = cu * 5 + pr;
        int valid = (pr < 5);
        int b = valid ? idx / 20 : 0, o = valid ? idx % 20 : 0;
        const f16* hp = sm.planeB + b * HP_STRIDE + kp * 64;
        const float* wo = Wo + (size_t)o * 512 + kp * 64;
        float a = 0.f;
        if (valid) {
#pragma unroll
            for (int k = 0; k < 64; k += 8) {
                f16x8 hv = *(const f16x8*)(hp + k);
                float4 wa = *(const float4*)(wo + k);
                float4 wb = *(const float4*)(wo + k + 4);
                a += (float)hv[0] * wa.x + (float)hv[1] * wa.y +
                     (float)hv[2] * wa.z + (float)hv[3] * wa.w +
                     (float)hv[4] * wb.x + (float)hv[5] * wb.y +
                     (float)hv[6] * wb.z + (float)hv[7] * wb.w;
            }
        }
        a += __shfl_down(a, 4, 8);
        a += __shfl_down(a, 2, 8);
        a += __shfl_down(a, 1, 8);
        if (valid && kp == 0)
            out[((size_t)(gb8 + b) * 1024 + (T_STEPS - 1)) * 20 + o] =
                sigm_(a + bo[o]);
    }
}

extern "C" void kernel_launch(void* const* d_in, const int* in_sizes, int n_in,
                              void* d_out, int out_size, void* d_ws, size_t ws_size,
                              hipStream_t stream) {
    const float* x   = (const float*)d_in[0];
    const float* Wx0 = (const float*)d_in[1];
    const float* bx0 = (const float*)d_in[2];
    const float* Wh0 = (const float*)d_in[3];
    const float* Wx1 = (const float*)d_in[4];
    const float* bx1 = (const float*)d_in[5];
    const float* Wh1 = (const float*)d_in[6];
    const float* Wo  = (const float*)d_in[7];
    const float* bo  = (const float*)d_in[8];
    float* out = (float*)d_out;
    char*  ws  = (char*)d_ws;

    if (ws_size < (size_t)WS_NEED) return;   // fail visibly (out stays poisoned)

    zero_ws_kernel<<<64, 256, 0, stream>>>((unsigned*)ws, WS_NEED / 4);
    lstm_persist<<<256, 256, 0, stream>>>(x, Wx0, bx0, Wh0, Wx1, bx1, Wh1,
                                          Wo, bo, out, ws);
}

// Round 6
// 6201.160 us; speedup vs baseline: 1.0207x; 1.0207x over previous
//
#include <hip/hip_runtime.h>

// ---------------------------------------------------------------------------
// Persistent 2-layer LSTM, MI355X. Round 6.
// 8 groups (blockIdx%8), 32 WGs/group, 8 batches/group. Weights in VGPRs.
// Coherence: all h-plane + flag traffic uses relaxed SYSTEM-scope (sc0|sc1
// bypass) ops -> coherent at LLC by construction; zero maintenance ops.
// Round-6: barrier = per-WG FLAG STORES (monotone step number), not a shared
// atomic counter. Round 1-4 serialized 32 RMWs/crossing at one LLC address
// (~2-3 us); flags are 32 independent plain stores + parallel polling.
// h planes are WG-major (256 B contiguous per WG -> full-line writes).
// Round-5's XCD-local experiment (hwreg read + L2-scope signal) deadlocked;
// reverted entirely -> pure LLC protocol, cannot hang.
// ---------------------------------------------------------------------------

#define T_STEPS 1024
#define WS_BAR_OFF 0                      // 8 groups * 64 u32 (256 B each)
#define WS_H0_OFF  2048                   // [8 g][2 parity][32 cu][8 b][16] f16
#define WS_H1_OFF  (2048 + 8*2*8*512*2)
#define WS_NEED    (WS_H1_OFF + 8*2*8*512*2)   // 264192 bytes

typedef _Float16 f16;
typedef _Float16 f16x8 __attribute__((ext_vector_type(8)));
typedef float    f32x4 __attribute__((ext_vector_type(4)));
typedef unsigned long long u64;

#define HP_STRIDE 520   // padded LDS plane row stride (f16)

__device__ __forceinline__ float sigm_(float x) {
    x = fminf(fmaxf(x, -30.f), 30.f);
    return 1.f / (1.f + __expf(-x));
}
__device__ __forceinline__ float tanh_(float x) {
    x = fminf(fmaxf(x, -15.f), 15.f);
    float e = __expf(-2.f * x);
    return (1.f - e) / (1.f + e);
}

// A-fragment for 16x16x32 f16 MFMA from a padded LDS plane.
// A[m=lane&15][k=(lane>>4)*8+j]; m = batch (0..7 valid, 8..15 -> zeros).
__device__ __forceinline__ f16x8 afrag_lds(const f16* __restrict__ hp, int kbase,
                                           int b, int q) {
    if (b < 8) {
        return *(const f16x8*)(hp + b * HP_STRIDE + kbase + q * 8);
    }
    f16x8 z = {(_Float16)0, (_Float16)0, (_Float16)0, (_Float16)0,
               (_Float16)0, (_Float16)0, (_Float16)0, (_Float16)0};
    return z;
}

__device__ __forceinline__ f16x8 pack8(float4 a, float4 b) {
    f16x8 f;
    f[0] = (f16)a.x; f[1] = (f16)a.y; f[2] = (f16)a.z; f[3] = (f16)a.w;
    f[4] = (f16)b.x; f[5] = (f16)b.y; f[6] = (f16)b.z; f[7] = (f16)b.w;
    return f;
}

// Poll the 4 flags covering the WGs whose data THIS thread will stage
// (cu' = j*8 + (tid>>5), j=0..3). Relaxed system loads = sc0sc1 bypass,
// no cache maintenance. Monotone flags -> no reset, no ABA.
__device__ __forceinline__ void wait4(const unsigned* f, unsigned target, int tid) {
    const unsigned* p0 = f + (tid >> 5);
    int spins = 0;
    for (;;) {
        unsigned a = __hip_atomic_load(p0,      __ATOMIC_RELAXED, __HIP_MEMORY_SCOPE_SYSTEM);
        unsigned b = __hip_atomic_load(p0 + 8,  __ATOMIC_RELAXED, __HIP_MEMORY_SCOPE_SYSTEM);
        unsigned c = __hip_atomic_load(p0 + 16, __ATOMIC_RELAXED, __HIP_MEMORY_SCOPE_SYSTEM);
        unsigned d = __hip_atomic_load(p0 + 24, __ATOMIC_RELAXED, __HIP_MEMORY_SCOPE_SYSTEM);
        unsigned ab = a < b ? a : b, cd = c < d ? c : d;
        if ((ab < cd ? ab : cd) >= target) break;
        __builtin_amdgcn_s_sleep(1);
        if (++spins > (1 << 20)) break;   // anti-hang safety valve
    }
}

// Stage one 8 KB WG-major h-plane into the padded LDS [batch][unit] plane.
// Global u64 index i: cu'=i>>5, b=(i>>2)&7, jj=i&3; unit base = cu'*16+jj*4.
// Thread tid handles i = j*256+tid (coalesced 2 KB per instruction).
__device__ __forceinline__ void stage_plane(const f16* __restrict__ gp,
                                            f16* __restrict__ dst, int tid) {
    const u64* g8 = (const u64*)gp;
    u64 v[4];
#pragma unroll
    for (int j = 0; j < 4; ++j)
        v[j] = __hip_atomic_load(g8 + j * 256 + tid, __ATOMIC_RELAXED,
                                 __HIP_MEMORY_SCOPE_SYSTEM);
#pragma unroll
    for (int j = 0; j < 4; ++j) {
        int i = j * 256 + tid;
        int cu_ = i >> 5, b = (i >> 2) & 7, jj = i & 3;
        *(u64*)(dst + b * HP_STRIDE + cu_ * 16 + jj * 4) = v[j];
    }
}

// x A-fragment for step t (zeros if t out of range).
__device__ __forceinline__ f16x8 load_xfrag(const float* __restrict__ x,
                                            int gb8, int t, int ln, int q) {
    f16x8 f = {(_Float16)0, (_Float16)0, (_Float16)0, (_Float16)0,
               (_Float16)0, (_Float16)0, (_Float16)0, (_Float16)0};
    if (ln < 8 && t < T_STEPS) {
        const float* xp = x + ((size_t)(gb8 + ln) * 1024 + t) * 21;
#pragma unroll
        for (int j = 0; j < 8; ++j) {
            int kl = q * 8 + j;
            if (kl < 21) f[j] = (f16)xp[kl];
        }
    }
    return f;
}

// Zeros must be visible at the LLC -> sc0sc1 stores.
__global__ void zero_ws_kernel(unsigned* __restrict__ p, int ndw) {
    int i = blockIdx.x * blockDim.x + threadIdx.x;
    int stride = gridDim.x * blockDim.x;
    for (; i < ndw; i += stride)
        __hip_atomic_store(p + i, 0u, __ATOMIC_RELAXED, __HIP_MEMORY_SCOPE_SYSTEM);
}

__global__ __launch_bounds__(256, 1)
void lstm_persist(const float* __restrict__ x,
                  const float* __restrict__ Wx0, const float* __restrict__ bx0,
                  const float* __restrict__ Wh0,
                  const float* __restrict__ Wx1, const float* __restrict__ bx1,
                  const float* __restrict__ Wh1,
                  const float* __restrict__ Wo,  const float* __restrict__ bo,
                  float* __restrict__ out, char* __restrict__ ws) {
    struct SM {
        float g[4][16][17];                      // +1 pad: conflict-free
        float c[2][8][16];                       // cell state [layer][b][u]
        float bias[2][4][16];                    // bx slices
        __align__(8)  f16 hout[8][16];           // activation -> packed store
        __align__(16) f16 planeA[8 * HP_STRIDE]; // persistent h0 plane
        __align__(16) f16 planeB[8 * HP_STRIDE]; // h1 scratch plane
        char  pad[70 * 1024];                    // force <=1 WG/CU
    };
    __shared__ SM sm;
    const int tid = threadIdx.x;
    if (tid == 0x00FFFFFFu) sm.pad[0] = 1;       // keep pad alive

    const int bid  = blockIdx.x;
    const int g    = bid & 7;     // group
    const int cu   = bid >> 3;    // rank 0..31 within group
    const int w    = tid >> 6;    // wave id = gate type (i,f,g,o)
    const int lane = tid & 63;
    const int ln   = lane & 15;
    const int q    = lane >> 4;
    const int gb8  = g * 8;       // first batch of group

    unsigned* barb  = (unsigned*)(ws + WS_BAR_OFF) + g * 64;
    unsigned* flagA = barb;         // 32 per-WG h0 flags (monotone step no.)
    unsigned* flagB = barb + 32;    // 32 per-WG h1 flags
    f16* H0g = (f16*)(ws + WS_H0_OFF) + g * 8192;   // 2 parity planes
    f16* H1g = (f16*)(ws + WS_H1_OFF) + g * 8192;

    // ---- LDS init -------------------------------------------------------
    ((float*)sm.c)[tid & 255] = 0.f;               // 2*8*16 = 256 floats
    if (tid < 128) {
        int u = tid & 15, w2 = (tid >> 4) & 3, L = tid >> 6;
        const float* bx = L ? bx1 : bx0;
        sm.bias[L][w2][u] = bx[(w2 << 9) + (cu << 4) + u];
    }

    // ---- persistent weight fragments in registers -----------------------
    const int row = (w << 9) + (cu << 4) + ln;      // gate row in [0,2048)
    f16x8 B0[17];   // layer0: k = [Wh0(512) ; Wx0(21 pad 32)]
    f16x8 B1[32];   // layer1: k = [Wx1(512) ; Wh1(512)]
    {
        const float* wh0r = Wh0 + (size_t)row * 512;
#pragma unroll
        for (int kk = 0; kk < 16; ++kk) {
            const float* p = wh0r + kk * 32 + q * 8;
            B0[kk] = pack8(*(const float4*)p, *(const float4*)(p + 4));
        }
        {
            const float* wx0r = Wx0 + (size_t)row * 21;
            f16x8 f;
#pragma unroll
            for (int j = 0; j < 8; ++j) {
                int kl = q * 8 + j;
                f[j] = (f16)((kl < 21) ? wx0r[kl] : 0.f);
            }
            B0[16] = f;
        }
        const float* wx1r = Wx1 + (size_t)row * 512;
        const float* wh1r = Wh1 + (size_t)row * 512;
#pragma unroll
        for (int kk = 0; kk < 32; ++kk) {
            int k0 = kk * 32 + q * 8;
            const float* p = (k0 < 512) ? (wx1r + k0) : (wh1r + (k0 - 512));
            B1[kk] = pack8(*(const float4*)p, *(const float4*)(p + 4));
        }
    }

    // ---- prologue: gates0(t=0) = Wx0 @ x(0)  (h0(-1)=0) ------------------
    {
        f16x8 xf = load_xfrag(x, gb8, 0, ln, q);
        f32x4 z = {0, 0, 0, 0};
        f32x4 acc = __builtin_amdgcn_mfma_f32_16x16x32_f16(xf, B0[16], z, 0, 0, 0);
#pragma unroll
        for (int r = 0; r < 4; ++r) sm.g[w][q * 4 + r][ln] = acc[r];
    }
    __syncthreads();

    for (int t = 0; t < T_STEPS; ++t) {
        const int wr = t & 1, rd = wr ^ 1;
        f16*       h0wr = H0g + wr * 4096;
        const f16* h1rd = H1g + rd * 4096;
        f16*       h1wr = H1g + wr * 4096;

        // ===== act0 + publish h0(t) (gates0 computed in prev tail) =========
        if (tid < 128) {
            int b = tid & 7, u = tid >> 3;
            float gi = sm.g[0][b][u] + sm.bias[0][0][u];
            float gf = sm.g[1][b][u] + sm.bias[0][1][u];
            float gg = sm.g[2][b][u] + sm.bias[0][2][u];
            float go = sm.g[3][b][u] + sm.bias[0][3][u];
            float iv = sigm_(gi), fv = sigm_(gf), gv = tanh_(gg), ov = sigm_(go);
            float c = sm.c[0][b][u];
            float cn = fv * c + iv * gv;
            sm.c[0][b][u] = cn;
            sm.hout[b][u] = (f16)(ov * tanh_(cn));
        }
        __syncthreads();
        if (tid < 32) {   // WG-major: 256 B contiguous per WG, full lines
            int b = tid >> 2, j = tid & 3;
            u64 v = *(const u64*)&sm.hout[b][j * 4];
            __hip_atomic_store((u64*)(h0wr + (cu << 7) + (b << 4) + (j << 2)), v,
                               __ATOMIC_RELAXED, __HIP_MEMORY_SCOPE_SYSTEM);
        }
        if (tid < 64) {   // wave-0-local drain (all h stores are wave 0's)
            asm volatile("s_waitcnt vmcnt(0)" ::: "memory");
            if (tid == 0)
                __hip_atomic_store(flagA + cu, (unsigned)(t + 1),
                                   __ATOMIC_RELAXED, __HIP_MEMORY_SCOPE_SYSTEM);
        }

        // ===== wait h1(t-1) flags, stage plane B ===========================
        wait4(flagB, (unsigned)t, tid);
        stage_plane(h1rd, sm.planeB, tid);
        __syncthreads();

        // ===== out-proj(t-1) on wave 1 + Wh1 @ h1(t-1) =====================
        if (t > 0 && tid >= 64 && tid < 128) {
            int wt = tid - 64;
            int pr = wt >> 3, kp = wt & 7;
            int idx = cu * 5 + pr;        // pr<5 valid
            int valid = (pr < 5);
            int b = valid ? idx / 20 : 0, o = valid ? idx % 20 : 0;
            const f16* hp = sm.planeB + b * HP_STRIDE + kp * 64;
            const float* wo = Wo + (size_t)o * 512 + kp * 64;
            float a = 0.f;
            if (valid) {
#pragma unroll
                for (int k = 0; k < 64; k += 8) {
                    f16x8 hv = *(const f16x8*)(hp + k);
                    float4 wa = *(const float4*)(wo + k);
                    float4 wb = *(const float4*)(wo + k + 4);
                    a += (float)hv[0] * wa.x + (float)hv[1] * wa.y +
                         (float)hv[2] * wa.z + (float)hv[3] * wa.w +
                         (float)hv[4] * wb.x + (float)hv[5] * wb.y +
                         (float)hv[6] * wb.z + (float)hv[7] * wb.w;
                }
            }
            a += __shfl_down(a, 4, 8);
            a += __shfl_down(a, 2, 8);
            a += __shfl_down(a, 1, 8);
            if (valid && kp == 0)
                out[((size_t)(gb8 + b) * 1024 + (t - 1)) * 20 + o] = sigm_(a + bo[o]);
        }
        f32x4 c0v = {0, 0, 0, 0}, c1v = {0, 0, 0, 0};
#pragma unroll
        for (int kk = 16; kk < 32; kk += 2) {
            f16x8 A0 = afrag_lds(sm.planeB, kk * 32 - 512, ln, q);
            f16x8 A1 = afrag_lds(sm.planeB, kk * 32 - 480, ln, q);
            c0v = __builtin_amdgcn_mfma_f32_16x16x32_f16(A0, B1[kk], c0v, 0, 0, 0);
            c1v = __builtin_amdgcn_mfma_f32_16x16x32_f16(A1, B1[kk + 1], c1v, 0, 0, 0);
        }

        // ===== wait h0(t) flags, stage persistent plane A ==================
        wait4(flagA, (unsigned)(t + 1), tid);
        stage_plane(h0wr, sm.planeA, tid);
        __syncthreads();

        // ===== Wx1 @ h0(t) =================================================
#pragma unroll
        for (int kk = 0; kk < 16; kk += 2) {
            f16x8 A0 = afrag_lds(sm.planeA, kk * 32, ln, q);
            f16x8 A1 = afrag_lds(sm.planeA, kk * 32 + 32, ln, q);
            c0v = __builtin_amdgcn_mfma_f32_16x16x32_f16(A0, B1[kk], c0v, 0, 0, 0);
            c1v = __builtin_amdgcn_mfma_f32_16x16x32_f16(A1, B1[kk + 1], c1v, 0, 0, 0);
        }
        {
            f32x4 acc = c0v + c1v;
#pragma unroll
            for (int r = 0; r < 4; ++r) sm.g[w][q * 4 + r][ln] = acc[r];
        }
        __syncthreads();

        // ===== act1 + publish h1(t) ========================================
        if (tid < 128) {
            int b = tid & 7, u = tid >> 3;
            float gi = sm.g[0][b][u] + sm.bias[1][0][u];
            float gf = sm.g[1][b][u] + sm.bias[1][1][u];
            float gg = sm.g[2][b][u] + sm.bias[1][2][u];
            float go = sm.g[3][b][u] + sm.bias[1][3][u];
            float iv = sigm_(gi), fv = sigm_(gf), gv = tanh_(gg), ov = sigm_(go);
            float c = sm.c[1][b][u];
            float cn = fv * c + iv * gv;
            sm.c[1][b][u] = cn;
            sm.hout[b][u] = (f16)(ov * tanh_(cn));
        }
        __syncthreads();
        if (tid < 32) {
            int b = tid >> 2, j = tid & 3;
            u64 v = *(const u64*)&sm.hout[b][j * 4];
            __hip_atomic_store((u64*)(h1wr + (cu << 7) + (b << 4) + (j << 2)), v,
                               __ATOMIC_RELAXED, __HIP_MEMORY_SCOPE_SYSTEM);
        }
        if (tid < 64) {
            asm volatile("s_waitcnt vmcnt(0)" ::: "memory");
            if (tid == 0)
                __hip_atomic_store(flagB + cu, (unsigned)(t + 1),
                                   __ATOMIC_RELAXED, __HIP_MEMORY_SCOPE_SYSTEM);
        }

        // ===== tail: gates0(t+1) = Wh0 @ h0(t) + Wx0 @ x(t+1) ==============
        {
            f16x8 xf = load_xfrag(x, gb8, t + 1, ln, q);
            f32x4 a0 = {0, 0, 0, 0}, a1 = {0, 0, 0, 0};
#pragma unroll
            for (int kk = 0; kk < 16; kk += 2) {
                f16x8 A0 = afrag_lds(sm.planeA, kk * 32, ln, q);
                f16x8 A1 = afrag_lds(sm.planeA, kk * 32 + 32, ln, q);
                a0 = __builtin_amdgcn_mfma_f32_16x16x32_f16(A0, B0[kk], a0, 0, 0, 0);
                a1 = __builtin_amdgcn_mfma_f32_16x16x32_f16(A1, B0[kk + 1], a1, 0, 0, 0);
            }
            a0 = __builtin_amdgcn_mfma_f32_16x16x32_f16(xf, B0[16], a0, 0, 0, 0);
            f32x4 acc = a0 + a1;
#pragma unroll
            for (int r = 0; r < 4; ++r) sm.g[w][q * 4 + r][ln] = acc[r];
        }
        __syncthreads();
    }

    // ===== epilogue: out-projection for t = T-1 =============================
    wait4(flagB, (unsigned)T_STEPS, tid);
    stage_plane(H1g + ((T_STEPS - 1) & 1) * 4096, sm.planeB, tid);
    __syncthreads();
    if (tid >= 64 && tid < 128) {
        int wt = tid - 64;
        int pr = wt >> 3, kp = wt & 7;
        int idx = cu * 5 + pr;
        int valid = (pr < 5);
        int b = valid ? idx / 20 : 0, o = valid ? idx % 20 : 0;
        const f16* hp = sm.planeB + b * HP_STRIDE + kp * 64;
        const float* wo = Wo + (size_t)o * 512 + kp * 64;
        float a = 0.f;
        if (valid) {
#pragma unroll
            for (int k = 0; k < 64; k += 8) {
                f16x8 hv = *(const f16x8*)(hp + k);
                float4 wa = *(const float4*)(wo + k);
                float4 wb = *(const float4*)(wo + k + 4);
                a += (float)hv[0] * wa.x + (float)hv[1] * wa.y +
                     (float)hv[2] * wa.z + (float)hv[3] * wa.w +
                     (float)hv[4] * wb.x + (float)hv[5] * wb.y +
                     (float)hv[6] * wb.z + (float)hv[7] * wb.w;
            }
        }
        a += __shfl_down(a, 4, 8);
        a += __shfl_down(a, 2, 8);
        a += __shfl_down(a, 1, 8);
        if (valid && kp == 0)
            out[((size_t)(gb8 + b) * 1024 + (T_STEPS - 1)) * 20 + o] =
                sigm_(a + bo[o]);
    }
}

extern "C" void kernel_launch(void* const* d_in, const int* in_sizes, int n_in,
                              void* d_out, int out_size, void* d_ws, size_t ws_size,
                              hipStream_t stream) {
    const float* x   = (const float*)d_in[0];
    const float* Wx0 = (const float*)d_in[1];
    const float* bx0 = (const float*)d_in[2];
    const float* Wh0 = (const float*)d_in[3];
    const float* Wx1 = (const float*)d_in[4];
    const float* bx1 = (const float*)d_in[5];
    const float* Wh1 = (const float*)d_in[6];
    const float* Wo  = (const float*)d_in[7];
    const float* bo  = (const float*)d_in[8];
    float* out = (float*)d_out;
    char*  ws  = (char*)d_ws;

    if (ws_size < (size_t)WS_NEED) return;   // fail visibly (out stays poisoned)

    zero_ws_kernel<<<64, 256, 0, stream>>>((unsigned*)ws, WS_NEED / 4);
    lstm_persist<<<256, 256, 0, stream>>>(x, Wx0, bx0, Wh0, Wx1, bx1, Wh1,
                                          Wo, bo, out, ws);
}